// Round 2
// baseline (1020.384 us; speedup 1.0000x reference)
//
#include <hip/hip_runtime.h>
#include <hip/hip_bf16.h>
#include <math.h>

// ---------------------------------------------------------------------------
// Qwen3 attention block: T=4096, HIDDEN=2048, 16 Q heads, 8 KV heads,
// HEAD_DIM=128, rope theta 1e6, rms eps 1e-6, causal.
// Inputs/outputs are FLOAT32 (per reference dtypes); bf16 used internally for
// MFMA with fp32 accumulation (test grants bf16-grade tolerance).
//
// ws layout (80 MB):
//   qkv  bf16 [4096][4096]
//   qn   bf16 [4096][2048]   (q after norm+rope, [t][h*128+d])
//   kn   bf16 [4096][1024]   (k after norm+rope, [t][kvh*128+d])
//   vt   bf16 [1024][4096]   (v transposed,     [kvh*128+d][t])
//   ao   bf16 [4096][2048]   (attention output, [t][h*128+d])
// ---------------------------------------------------------------------------

typedef __bf16 bf16;
typedef __bf16 bf16x8 __attribute__((ext_vector_type(8)));
typedef float  f32x4  __attribute__((ext_vector_type(4)));

__device__ __forceinline__ f32x4 mfma16(bf16x8 a, bf16x8 b, f32x4 c) {
  return __builtin_amdgcn_mfma_f32_16x16x32_bf16(a, b, c, 0, 0, 0);
}

// load 8 contiguous elements from global (fp32 or bf16) -> 8 bf16 in LDS
__device__ __forceinline__ void load8_to_lds(const float* src, bf16* dst) {
  float4 a = *reinterpret_cast<const float4*>(src);
  float4 b = *reinterpret_cast<const float4*>(src + 4);
  bf16x8 v = {(bf16)a.x, (bf16)a.y, (bf16)a.z, (bf16)a.w,
              (bf16)b.x, (bf16)b.y, (bf16)b.z, (bf16)b.w};
  *reinterpret_cast<bf16x8*>(dst) = v;
}
__device__ __forceinline__ void load8_to_lds(const bf16* src, bf16* dst) {
  *reinterpret_cast<uint4*>(dst) = *reinterpret_cast<const uint4*>(src);
}
__device__ __forceinline__ void store_c(float* p, float v) { *p = v; }
__device__ __forceinline__ void store_c(bf16* p, float v) { *p = (bf16)v; }

// ---------------------------------------------------------------------------
// C[M][N] = A[M][K] @ B[N][K]^T   (fp32 accumulate)
// block: 256 threads, 128x128 C tile; 4 waves in 2x2, each 64x64 (4x4 MFMA)
// ---------------------------------------------------------------------------
template <typename TA, typename TB, typename TC>
__global__ __launch_bounds__(256) void gemm_bt(const TA* __restrict__ A,
                                               const TB* __restrict__ B,
                                               TC* __restrict__ C,
                                               int M, int N, int K) {
  // stride 40 (=32+8) elems: breaks 8-way bank aliasing, keeps 16B alignment.
  __shared__ __align__(16) bf16 As[128 * 40];
  __shared__ __align__(16) bf16 Bs[128 * 40];

  const int tid  = threadIdx.x;
  const int wave = tid >> 6, lane = tid & 63;
  const int quad = lane >> 4, l16 = lane & 15;
  const int wm = (wave >> 1) * 64, wn = (wave & 1) * 64;
  const int n0 = blockIdx.x * 128, m0 = blockIdx.y * 128;

  const f32x4 zero = {0.f, 0.f, 0.f, 0.f};
  f32x4 acc[4][4];
#pragma unroll
  for (int i = 0; i < 4; ++i)
#pragma unroll
    for (int j = 0; j < 4; ++j) acc[i][j] = zero;

  for (int k0 = 0; k0 < K; k0 += 32) {
    // stage A,B tiles: 128 rows x 32 cols each; 256 thr * 8 elem * 2 iters
#pragma unroll
    for (int it = 0; it < 2; ++it) {
      int linear = it * 2048 + tid * 8;
      int r = linear >> 5, c = linear & 31;
      load8_to_lds(&A[(size_t)(m0 + r) * K + k0 + c], &As[r * 40 + c]);
      load8_to_lds(&B[(size_t)(n0 + r) * K + k0 + c], &Bs[r * 40 + c]);
    }
    __syncthreads();

    bf16x8 af[4], bfr[4];
#pragma unroll
    for (int i = 0; i < 4; ++i)
      af[i] = *reinterpret_cast<const bf16x8*>(&As[(wm + i * 16 + l16) * 40 + quad * 8]);
#pragma unroll
    for (int j = 0; j < 4; ++j)
      bfr[j] = *reinterpret_cast<const bf16x8*>(&Bs[(wn + j * 16 + l16) * 40 + quad * 8]);
#pragma unroll
    for (int i = 0; i < 4; ++i)
#pragma unroll
      for (int j = 0; j < 4; ++j)
        acc[i][j] = mfma16(af[i], bfr[j], acc[i][j]);
    __syncthreads();
  }

  // epilogue: C/D layout col=lane&15, row=quad*4+reg (verified m89/m91)
#pragma unroll
  for (int i = 0; i < 4; ++i)
#pragma unroll
    for (int j = 0; j < 4; ++j)
#pragma unroll
      for (int r = 0; r < 4; ++r) {
        int row = m0 + wm + i * 16 + quad * 4 + r;
        int col = n0 + wn + j * 16 + l16;
        store_c(&C[(size_t)row * N + col], acc[i][j][r]);
      }
}

// ---------------------------------------------------------------------------
// Per-(token, head) RMS norm + rope. grid (4096, 24): y<16 -> q head, else k.
// block 128 threads = one head row.
// ---------------------------------------------------------------------------
__global__ __launch_bounds__(128) void norm_rope(const bf16* __restrict__ qkv,
                                                 const float* __restrict__ qw,
                                                 const float* __restrict__ kw,
                                                 const int* __restrict__ pos,
                                                 bf16* __restrict__ qn,
                                                 bf16* __restrict__ kn) {
  const int t   = blockIdx.x;
  const int hr  = blockIdx.y;
  const int tid = threadIdx.x;
  const bool isq = hr < 16;
  const int col  = isq ? hr * 128 : 2048 + (hr - 16) * 128;

  float x = (float)qkv[(size_t)t * 4096 + col + tid];
  float ss = x * x;
#pragma unroll
  for (int o = 32; o >= 1; o >>= 1) ss += __shfl_xor(ss, o);
  __shared__ float part[2];
  __shared__ float sh[128];
  if ((tid & 63) == 0) part[tid >> 6] = ss;
  __syncthreads();
  float total = part[0] + part[1];
  float rms = rsqrtf(total * (1.0f / 128.0f) + 1e-6f);
  const float* w = isq ? qw : kw;
  float xn = x * rms * w[tid];
  sh[tid] = xn;
  __syncthreads();

  int d = tid & 63;
  // inv_freq = 1e6^(-d/64) = 2^(-d*log2(1e6)/64)
  float inv = exp2f((float)d * (-19.93156856932417f / 64.0f));
  float fr = (float)pos[t] * inv;
  float sn, cs;
  sincosf(fr, &sn, &cs);
  float out = (tid < 64) ? (sh[tid] * cs - sh[tid + 64] * sn)
                         : (sh[tid] * cs + sh[tid - 64] * sn);
  if (isq) qn[(size_t)t * 2048 + hr * 128 + tid] = (bf16)out;
  else     kn[(size_t)t * 1024 + (hr - 16) * 128 + tid] = (bf16)out;
}

// ---------------------------------------------------------------------------
// One-time V transpose: vt[kvh*128+d][t] = qkv[t][3072 + kvh*128 + d]
// grid (64 t-tiles, 8 kvh), block 256. LDS tile [128 d][64 t] stride 72.
// ---------------------------------------------------------------------------
__global__ __launch_bounds__(256) void transpose_v(const bf16* __restrict__ qkv,
                                                   bf16* __restrict__ vt) {
  __shared__ __align__(16) bf16 tile[128 * 72];
  const int t0 = blockIdx.x * 64, kvh = blockIdx.y;
  const int tid = threadIdx.x;
#pragma unroll
  for (int it = 0; it < 2; ++it) {
    int linear = it * 4096 + tid * 16;
    int r = linear >> 7, c = linear & 127;  // t row r, dim c..c+15
    union { uint4 v; bf16 e[8]; } u0, u1;
    u0.v = *reinterpret_cast<const uint4*>(
        &qkv[(size_t)(t0 + r) * 4096 + 3072 + kvh * 128 + c]);
    u1.v = *reinterpret_cast<const uint4*>(
        &qkv[(size_t)(t0 + r) * 4096 + 3072 + kvh * 128 + c + 8]);
#pragma unroll
    for (int j = 0; j < 8; ++j) tile[(c + j) * 72 + r] = u0.e[j];
#pragma unroll
    for (int j = 0; j < 8; ++j) tile[(c + 8 + j) * 72 + r] = u1.e[j];
  }
  __syncthreads();
#pragma unroll
  for (int it = 0; it < 4; ++it) {
    int linear = it * 2048 + tid * 8;
    int d = linear >> 6, c = linear & 63;  // dim d, t cols c..c+7
    uint4 v = *reinterpret_cast<const uint4*>(&tile[d * 72 + c]);
    *reinterpret_cast<uint4*>(&vt[(size_t)(kvh * 128 + d) * 4096 + t0 + c]) = v;
  }
}

// ---------------------------------------------------------------------------
// Flash attention, causal, GQA rep=2. grid (64 q-blocks, 16 heads), block 256.
// Each wave owns 16 q rows; K-tiles of 64 iterated up to the diagonal.
// ---------------------------------------------------------------------------
__global__ __launch_bounds__(256) void attn(const bf16* __restrict__ q,
                                            const bf16* __restrict__ k,
                                            const bf16* __restrict__ vt,
                                            bf16* __restrict__ out) {
  __shared__ __align__(16) bf16 Ks[64 * 136];   // [kv row][dim], stride 136
  __shared__ __align__(16) bf16 Vs[128 * 72];   // [dim][kv row], stride 72
  __shared__ __align__(16) bf16 Ps[4][16 * 72]; // per wave [q row][kv col]

  const int h = blockIdx.y, kvh = h >> 1;
  const int q0 = blockIdx.x * 64;
  const int tid = threadIdx.x;
  const int wave = tid >> 6, lane = tid & 63;
  const int quad = lane >> 4, l16 = lane & 15;
  const float scale = 0.08838834764831845f;  // 128^-0.5

  // Q fragments live for the whole block: A[m=l16][k=ks*32+quad*8+j]
  bf16x8 qf[4];
  const int qrow = q0 + wave * 16 + l16;
#pragma unroll
  for (int s = 0; s < 4; ++s)
    qf[s] = *reinterpret_cast<const bf16x8*>(
        &q[(size_t)qrow * 2048 + h * 128 + s * 32 + quad * 8]);

  const f32x4 zero = {0.f, 0.f, 0.f, 0.f};
  f32x4 o_acc[8];
#pragma unroll
  for (int d = 0; d < 8; ++d) o_acc[d] = zero;
  float m_i[4], l_i[4];
#pragma unroll
  for (int r = 0; r < 4; ++r) { m_i[r] = -INFINITY; l_i[r] = 0.f; }

  for (int k0 = 0; k0 < q0 + 64; k0 += 64) {
    // ---- stage K tile [64][128] and V^T tile [128][64] ----
#pragma unroll
    for (int it = 0; it < 4; ++it) {
      int linear = it * 2048 + tid * 8;
      int r = linear >> 7, c = linear & 127;
      *reinterpret_cast<uint4*>(&Ks[r * 136 + c]) =
          *reinterpret_cast<const uint4*>(&k[(size_t)(k0 + r) * 1024 + kvh * 128 + c]);
    }
#pragma unroll
    for (int it = 0; it < 4; ++it) {
      int linear = it * 2048 + tid * 8;
      int d = linear >> 6, c = linear & 63;
      *reinterpret_cast<uint4*>(&Vs[d * 72 + c]) =
          *reinterpret_cast<const uint4*>(&vt[(size_t)(kvh * 128 + d) * 4096 + k0 + c]);
    }
    __syncthreads();

    // ---- S = Q K^T : wave computes 16 q rows x 64 kv cols ----
    f32x4 s_acc[4];
#pragma unroll
    for (int nt = 0; nt < 4; ++nt) {
      f32x4 sa = zero;
#pragma unroll
      for (int ks = 0; ks < 4; ++ks) {
        bf16x8 bfg = *reinterpret_cast<const bf16x8*>(
            &Ks[(nt * 16 + l16) * 136 + ks * 32 + quad * 8]);
        sa = mfma16(qf[ks], bfg, sa);
      }
      s_acc[nt] = sa;
    }

    // scale + causal mask (only the diagonal tile needs masking)
    const bool diag = (k0 == q0);
#pragma unroll
    for (int nt = 0; nt < 4; ++nt)
#pragma unroll
      for (int r = 0; r < 4; ++r) {
        float s = s_acc[nt][r] * scale;
        if (diag) {
          int tq = wave * 16 + quad * 4 + r;
          int tk = nt * 16 + l16;
          if (tk > tq) s = -1e30f;
        }
        s_acc[nt][r] = s;
      }

    // ---- online softmax (per q row; 16 consecutive lanes share a row) ----
#pragma unroll
    for (int r = 0; r < 4; ++r) {
      float mx = fmaxf(fmaxf(s_acc[0][r], s_acc[1][r]),
                       fmaxf(s_acc[2][r], s_acc[3][r]));
#pragma unroll
      for (int o = 1; o < 16; o <<= 1) mx = fmaxf(mx, __shfl_xor(mx, o));
      float mn = fmaxf(m_i[r], mx);
      float al = expf(m_i[r] - mn);
      m_i[r] = mn;
      float rs = 0.f;
#pragma unroll
      for (int nt = 0; nt < 4; ++nt) {
        float p = expf(s_acc[nt][r] - mn);
        s_acc[nt][r] = p;
        rs += p;
      }
#pragma unroll
      for (int o = 1; o < 16; o <<= 1) rs += __shfl_xor(rs, o);
      l_i[r] = l_i[r] * al + rs;
#pragma unroll
      for (int d = 0; d < 8; ++d) o_acc[d][r] *= al;
    }

    // ---- P -> LDS (C layout -> A layout round trip, m120 pattern) ----
#pragma unroll
    for (int nt = 0; nt < 4; ++nt)
#pragma unroll
      for (int r = 0; r < 4; ++r)
        Ps[wave][(quad * 4 + r) * 72 + nt * 16 + l16] = (bf16)s_acc[nt][r];
    __syncthreads();

    // ---- O += P V ----
#pragma unroll
    for (int ks = 0; ks < 2; ++ks) {
      bf16x8 pa = *reinterpret_cast<const bf16x8*>(
          &Ps[wave][l16 * 72 + ks * 32 + quad * 8]);
#pragma unroll
      for (int d = 0; d < 8; ++d) {
        bf16x8 vb = *reinterpret_cast<const bf16x8*>(
            &Vs[(d * 16 + l16) * 72 + ks * 32 + quad * 8]);
        o_acc[d] = mfma16(pa, vb, o_acc[d]);
      }
    }
    __syncthreads();
  }

  // ---- epilogue: O /= l, write [t][h*128+d] ----
#pragma unroll
  for (int d = 0; d < 8; ++d)
#pragma unroll
    for (int r = 0; r < 4; ++r) {
      float v = o_acc[d][r] / l_i[r];
      out[(size_t)(q0 + wave * 16 + quad * 4 + r) * 2048 + h * 128 + d * 16 + l16] =
          (bf16)v;
    }
}

// ---------------------------------------------------------------------------
extern "C" void kernel_launch(void* const* d_in, const int* in_sizes, int n_in,
                              void* d_out, int out_size, void* d_ws, size_t ws_size,
                              hipStream_t stream) {
  const float* hidden = (const float*)d_in[0];  // [4096][2048]
  const float* qkv_w  = (const float*)d_in[1];  // [4096][2048]
  const float* qnw    = (const float*)d_in[2];  // [128]
  const float* knw    = (const float*)d_in[3];  // [128]
  const float* o_w    = (const float*)d_in[4];  // [2048][2048]
  const int*   pos    = (const int*)d_in[5];    // [4096]

  bf16* qkv = (bf16*)d_ws;                       // 4096*4096
  bf16* qn  = qkv + (size_t)4096 * 4096;         // 4096*2048
  bf16* kn  = qn  + (size_t)4096 * 2048;         // 4096*1024
  bf16* vt  = kn  + (size_t)4096 * 1024;         // 1024*4096
  bf16* ao  = vt  + (size_t)1024 * 4096;         // 4096*2048
  float* out = (float*)d_out;                    // fp32 output

  gemm_bt<<<dim3(32, 32), 256, 0, stream>>>(hidden, qkv_w, qkv, 4096, 4096, 2048);
  norm_rope<<<dim3(4096, 24), 128, 0, stream>>>(qkv, qnw, knw, pos, qn, kn);
  transpose_v<<<dim3(64, 8), 256, 0, stream>>>(qkv, vt);
  attn<<<dim3(64, 16), 256, 0, stream>>>(qn, kn, vt, ao);
  gemm_bt<<<dim3(16, 32), 256, 0, stream>>>(ao, o_w, out, 4096, 2048, 2048);
}

// Round 3
// 868.607 us; speedup vs baseline: 1.1747x; 1.1747x over previous
//
#include <hip/hip_runtime.h>
#include <hip/hip_bf16.h>
#include <math.h>

// ---------------------------------------------------------------------------
// Qwen3 attention block: T=4096, HIDDEN=2048, 16 Q heads, 8 KV heads,
// HEAD_DIM=128, rope theta 1e6, rms eps 1e-6, causal.
// fp32 in/out; bf16 internally for MFMA with fp32 accumulation.
//
// ws layout (80 MB):
//   qkv  bf16 [4096][4096]
//   qn   bf16 [4096][2048]   (q after norm+rope, [t][h*128+d])
//   kn   bf16 [4096][1024]   (k after norm+rope, [t][kvh*128+d])
//   vt   bf16 [1024][4096]   (v transposed,     [kvh*128+d][t])
//   ao   bf16 [4096][2048]   (attention output, [t][h*128+d])
// ---------------------------------------------------------------------------

typedef __bf16 bf16;
typedef __bf16 bf16x8 __attribute__((ext_vector_type(8)));
typedef float  f32x4  __attribute__((ext_vector_type(4)));

__device__ __forceinline__ f32x4 mfma16(bf16x8 a, bf16x8 b, f32x4 c) {
  return __builtin_amdgcn_mfma_f32_16x16x32_bf16(a, b, c, 0, 0, 0);
}

__device__ __forceinline__ void load8_to_lds(const float* src, bf16* dst) {
  float4 a = *reinterpret_cast<const float4*>(src);
  float4 b = *reinterpret_cast<const float4*>(src + 4);
  bf16x8 v = {(bf16)a.x, (bf16)a.y, (bf16)a.z, (bf16)a.w,
              (bf16)b.x, (bf16)b.y, (bf16)b.z, (bf16)b.w};
  *reinterpret_cast<bf16x8*>(dst) = v;
}
__device__ __forceinline__ void load8_to_lds(const bf16* src, bf16* dst) {
  *reinterpret_cast<uint4*>(dst) = *reinterpret_cast<const uint4*>(src);
}
__device__ __forceinline__ void store_c(float* p, float v) { *p = v; }
__device__ __forceinline__ void store_c(bf16* p, float v) { *p = (bf16)v; }

// ---------------------------------------------------------------------------
// C[M][N] = A[M][K] @ B[N][K]^T   (fp32 accumulate)  — unchanged from R1
// ---------------------------------------------------------------------------
template <typename TA, typename TB, typename TC>
__global__ __launch_bounds__(256) void gemm_bt(const TA* __restrict__ A,
                                               const TB* __restrict__ B,
                                               TC* __restrict__ C,
                                               int M, int N, int K) {
  __shared__ __align__(16) bf16 As[128 * 40];
  __shared__ __align__(16) bf16 Bs[128 * 40];

  const int tid  = threadIdx.x;
  const int wave = tid >> 6, lane = tid & 63;
  const int quad = lane >> 4, l16 = lane & 15;
  const int wm = (wave >> 1) * 64, wn = (wave & 1) * 64;
  const int n0 = blockIdx.x * 128, m0 = blockIdx.y * 128;

  const f32x4 zero = {0.f, 0.f, 0.f, 0.f};
  f32x4 acc[4][4];
#pragma unroll
  for (int i = 0; i < 4; ++i)
#pragma unroll
    for (int j = 0; j < 4; ++j) acc[i][j] = zero;

  for (int k0 = 0; k0 < K; k0 += 32) {
#pragma unroll
    for (int it = 0; it < 2; ++it) {
      int linear = it * 2048 + tid * 8;
      int r = linear >> 5, c = linear & 31;
      load8_to_lds(&A[(size_t)(m0 + r) * K + k0 + c], &As[r * 40 + c]);
      load8_to_lds(&B[(size_t)(n0 + r) * K + k0 + c], &Bs[r * 40 + c]);
    }
    __syncthreads();

    bf16x8 af[4], bfr[4];
#pragma unroll
    for (int i = 0; i < 4; ++i)
      af[i] = *reinterpret_cast<const bf16x8*>(&As[(wm + i * 16 + l16) * 40 + quad * 8]);
#pragma unroll
    for (int j = 0; j < 4; ++j)
      bfr[j] = *reinterpret_cast<const bf16x8*>(&Bs[(wn + j * 16 + l16) * 40 + quad * 8]);
#pragma unroll
    for (int i = 0; i < 4; ++i)
#pragma unroll
      for (int j = 0; j < 4; ++j)
        acc[i][j] = mfma16(af[i], bfr[j], acc[i][j]);
    __syncthreads();
  }

#pragma unroll
  for (int i = 0; i < 4; ++i)
#pragma unroll
    for (int j = 0; j < 4; ++j)
#pragma unroll
      for (int r = 0; r < 4; ++r) {
        int row = m0 + wm + i * 16 + quad * 4 + r;
        int col = n0 + wn + j * 16 + l16;
        store_c(&C[(size_t)row * N + col], acc[i][j][r]);
      }
}

// ---------------------------------------------------------------------------
// Per-(token, head) RMS norm + rope — unchanged from R1
// ---------------------------------------------------------------------------
__global__ __launch_bounds__(128) void norm_rope(const bf16* __restrict__ qkv,
                                                 const float* __restrict__ qw,
                                                 const float* __restrict__ kw,
                                                 const int* __restrict__ pos,
                                                 bf16* __restrict__ qn,
                                                 bf16* __restrict__ kn) {
  const int t   = blockIdx.x;
  const int hr  = blockIdx.y;
  const int tid = threadIdx.x;
  const bool isq = hr < 16;
  const int col  = isq ? hr * 128 : 2048 + (hr - 16) * 128;

  float x = (float)qkv[(size_t)t * 4096 + col + tid];
  float ss = x * x;
#pragma unroll
  for (int o = 32; o >= 1; o >>= 1) ss += __shfl_xor(ss, o);
  __shared__ float part[2];
  __shared__ float sh[128];
  if ((tid & 63) == 0) part[tid >> 6] = ss;
  __syncthreads();
  float total = part[0] + part[1];
  float rms = rsqrtf(total * (1.0f / 128.0f) + 1e-6f);
  const float* w = isq ? qw : kw;
  float xn = x * rms * w[tid];
  sh[tid] = xn;
  __syncthreads();

  int d = tid & 63;
  float inv = exp2f((float)d * (-19.93156856932417f / 64.0f));
  float fr = (float)pos[t] * inv;
  float sn, cs;
  sincosf(fr, &sn, &cs);
  float out = (tid < 64) ? (sh[tid] * cs - sh[tid + 64] * sn)
                         : (sh[tid] * cs + sh[tid - 64] * sn);
  if (isq) qn[(size_t)t * 2048 + hr * 128 + tid] = (bf16)out;
  else     kn[(size_t)t * 1024 + (hr - 16) * 128 + tid] = (bf16)out;
}

// ---------------------------------------------------------------------------
// One-time V transpose — unchanged from R1
// ---------------------------------------------------------------------------
__global__ __launch_bounds__(256) void transpose_v(const bf16* __restrict__ qkv,
                                                   bf16* __restrict__ vt) {
  __shared__ __align__(16) bf16 tile[128 * 72];
  const int t0 = blockIdx.x * 64, kvh = blockIdx.y;
  const int tid = threadIdx.x;
#pragma unroll
  for (int it = 0; it < 2; ++it) {
    int linear = it * 4096 + tid * 16;
    int r = linear >> 7, c = linear & 127;
    union { uint4 v; bf16 e[8]; } u0, u1;
    u0.v = *reinterpret_cast<const uint4*>(
        &qkv[(size_t)(t0 + r) * 4096 + 3072 + kvh * 128 + c]);
    u1.v = *reinterpret_cast<const uint4*>(
        &qkv[(size_t)(t0 + r) * 4096 + 3072 + kvh * 128 + c + 8]);
#pragma unroll
    for (int j = 0; j < 8; ++j) tile[(c + j) * 72 + r] = u0.e[j];
#pragma unroll
    for (int j = 0; j < 8; ++j) tile[(c + 8 + j) * 72 + r] = u1.e[j];
  }
  __syncthreads();
#pragma unroll
  for (int it = 0; it < 4; ++it) {
    int linear = it * 2048 + tid * 8;
    int d = linear >> 6, c = linear & 63;
    uint4 v = *reinterpret_cast<const uint4*>(&tile[d * 72 + c]);
    *reinterpret_cast<uint4*>(&vt[(size_t)(kvh * 128 + d) * 4096 + t0 + c]) = v;
  }
}

// ---------------------------------------------------------------------------
// Flash attention v2. grid (64 swizzled q-tiles, 8 kv heads), block 256.
// Block handles BOTH q-heads of its kv head (shared K/V staging):
//   wave>>1 = head select, wave&1 = 32-row half of the 64-row q-tile.
// Each wave: 32 q rows (2 m-frags), k-tile 64 → 64 MFMA/wave/tile.
// 2 barriers/tile (Ps round-trip is wave-private, no barrier needed).
// ---------------------------------------------------------------------------
__global__ __launch_bounds__(256) void attn(const bf16* __restrict__ q,
                                            const bf16* __restrict__ k,
                                            const bf16* __restrict__ vt,
                                            bf16* __restrict__ out) {
  __shared__ __align__(16) bf16 Ks[64 * 136];    // [kv row][dim]
  __shared__ __align__(16) bf16 Vs[128 * 72];    // [dim][kv row]
  __shared__ __align__(16) bf16 Ps[4][32 * 72];  // per wave [q row][kv col]

  const int kvh = blockIdx.y;
  const int bx  = blockIdx.x;
  // long/short pairing: adjacent dispatch ids get (longest, shortest, ...)
  const int qt  = (bx & 1) ? (bx >> 1) : (63 - (bx >> 1));
  const int q0  = qt * 64;

  const int tid = threadIdx.x;
  const int wave = tid >> 6, lane = tid & 63;
  const int quad = lane >> 4, l16 = lane & 15;
  const int head = 2 * kvh + (wave >> 1);
  const int mbase = q0 + (wave & 1) * 32;  // this wave's first q row
  const float scale = 0.08838834764831845f;  // 128^-0.5

  // Q fragments for 2 m-tiles: A[m=l16][k=ks*32+quad*8+j]
  bf16x8 qf[2][4];
#pragma unroll
  for (int mi = 0; mi < 2; ++mi)
#pragma unroll
    for (int s = 0; s < 4; ++s)
      qf[mi][s] = *reinterpret_cast<const bf16x8*>(
          &q[(size_t)(mbase + mi * 16 + l16) * 2048 + head * 128 + s * 32 + quad * 8]);

  const f32x4 zero = {0.f, 0.f, 0.f, 0.f};
  f32x4 o_acc[2][8];
#pragma unroll
  for (int mi = 0; mi < 2; ++mi)
#pragma unroll
    for (int d = 0; d < 8; ++d) o_acc[mi][d] = zero;
  float m_i[2][4], l_i[2][4];
#pragma unroll
  for (int mi = 0; mi < 2; ++mi)
#pragma unroll
    for (int r = 0; r < 4; ++r) { m_i[mi][r] = -INFINITY; l_i[mi][r] = 0.f; }

  for (int k0 = 0; k0 < q0 + 64; k0 += 64) {
    // ---- stage K tile [64][128] and V^T tile [128][64] ----
#pragma unroll
    for (int it = 0; it < 4; ++it) {
      int linear = it * 2048 + tid * 8;
      int r = linear >> 7, c = linear & 127;
      *reinterpret_cast<uint4*>(&Ks[r * 136 + c]) =
          *reinterpret_cast<const uint4*>(&k[(size_t)(k0 + r) * 1024 + kvh * 128 + c]);
    }
#pragma unroll
    for (int it = 0; it < 4; ++it) {
      int linear = it * 2048 + tid * 8;
      int d = linear >> 6, c = linear & 63;
      *reinterpret_cast<uint4*>(&Vs[d * 72 + c]) =
          *reinterpret_cast<const uint4*>(&vt[(size_t)(kvh * 128 + d) * 4096 + k0 + c]);
    }
    __syncthreads();

    // ---- S = Q K^T : 32 q rows x 64 kv cols per wave ----
    f32x4 s_acc[2][4];
#pragma unroll
    for (int nt = 0; nt < 4; ++nt) {
      bf16x8 kf[4];
#pragma unroll
      for (int ks = 0; ks < 4; ++ks)
        kf[ks] = *reinterpret_cast<const bf16x8*>(
            &Ks[(nt * 16 + l16) * 136 + ks * 32 + quad * 8]);
#pragma unroll
      for (int mi = 0; mi < 2; ++mi) {
        f32x4 sa = zero;
#pragma unroll
        for (int ks = 0; ks < 4; ++ks) sa = mfma16(qf[mi][ks], kf[ks], sa);
        s_acc[mi][nt] = sa;
      }
    }

    // scale + causal mask (diagonal tile only)
    const bool diag = (k0 == q0);
#pragma unroll
    for (int mi = 0; mi < 2; ++mi)
#pragma unroll
      for (int nt = 0; nt < 4; ++nt)
#pragma unroll
        for (int r = 0; r < 4; ++r) {
          float s = s_acc[mi][nt][r] * scale;
          if (diag) {
            int tq = (wave & 1) * 32 + mi * 16 + quad * 4 + r;
            int tk = nt * 16 + l16;
            if (tk > tq) s = -1e30f;
          }
          s_acc[mi][nt][r] = s;
        }

    // ---- online softmax: 8 independent row-chains per wave ----
#pragma unroll
    for (int mi = 0; mi < 2; ++mi)
#pragma unroll
      for (int r = 0; r < 4; ++r) {
        float mx = fmaxf(fmaxf(s_acc[mi][0][r], s_acc[mi][1][r]),
                         fmaxf(s_acc[mi][2][r], s_acc[mi][3][r]));
#pragma unroll
        for (int o = 1; o < 16; o <<= 1) mx = fmaxf(mx, __shfl_xor(mx, o));
        float mn = fmaxf(m_i[mi][r], mx);
        float al = expf(m_i[mi][r] - mn);
        m_i[mi][r] = mn;
        float rs = 0.f;
#pragma unroll
        for (int nt = 0; nt < 4; ++nt) {
          float p = expf(s_acc[mi][nt][r] - mn);
          s_acc[mi][nt][r] = p;
          rs += p;
        }
#pragma unroll
        for (int o = 1; o < 16; o <<= 1) rs += __shfl_xor(rs, o);
        l_i[mi][r] = l_i[mi][r] * al + rs;
#pragma unroll
        for (int d = 0; d < 8; ++d) o_acc[mi][d][r] *= al;
      }

    // ---- P -> LDS (C layout -> A layout). Ps is wave-private: NO barrier.
#pragma unroll
    for (int mi = 0; mi < 2; ++mi)
#pragma unroll
      for (int nt = 0; nt < 4; ++nt)
#pragma unroll
        for (int r = 0; r < 4; ++r)
          Ps[wave][(mi * 16 + quad * 4 + r) * 72 + nt * 16 + l16] =
              (bf16)s_acc[mi][nt][r];

    // ---- O += P V ----
#pragma unroll
    for (int ks = 0; ks < 2; ++ks) {
      bf16x8 pa[2];
#pragma unroll
      for (int mi = 0; mi < 2; ++mi)
        pa[mi] = *reinterpret_cast<const bf16x8*>(
            &Ps[wave][(mi * 16 + l16) * 72 + ks * 32 + quad * 8]);
#pragma unroll
      for (int d = 0; d < 8; ++d) {
        bf16x8 vb = *reinterpret_cast<const bf16x8*>(
            &Vs[(d * 16 + l16) * 72 + ks * 32 + quad * 8]);
#pragma unroll
        for (int mi = 0; mi < 2; ++mi)
          o_acc[mi][d] = mfma16(pa[mi], vb, o_acc[mi][d]);
      }
    }
    __syncthreads();  // protects Ks/Vs restage
  }

  // ---- epilogue: O /= l, write [t][h*128+d] ----
#pragma unroll
  for (int mi = 0; mi < 2; ++mi)
#pragma unroll
    for (int d = 0; d < 8; ++d)
#pragma unroll
      for (int r = 0; r < 4; ++r) {
        float v = o_acc[mi][d][r] / l_i[mi][r];
        out[(size_t)(mbase + mi * 16 + quad * 4 + r) * 2048 + head * 128 +
            d * 16 + l16] = (bf16)v;
      }
}

// ---------------------------------------------------------------------------
extern "C" void kernel_launch(void* const* d_in, const int* in_sizes, int n_in,
                              void* d_out, int out_size, void* d_ws, size_t ws_size,
                              hipStream_t stream) {
  const float* hidden = (const float*)d_in[0];
  const float* qkv_w  = (const float*)d_in[1];
  const float* qnw    = (const float*)d_in[2];
  const float* knw    = (const float*)d_in[3];
  const float* o_w    = (const float*)d_in[4];
  const int*   pos    = (const int*)d_in[5];

  bf16* qkv = (bf16*)d_ws;                       // 4096*4096
  bf16* qn  = qkv + (size_t)4096 * 4096;         // 4096*2048
  bf16* kn  = qn  + (size_t)4096 * 2048;         // 4096*1024
  bf16* vt  = kn  + (size_t)4096 * 1024;         // 1024*4096
  bf16* ao  = vt  + (size_t)1024 * 4096;         // 4096*2048
  float* out = (float*)d_out;

  gemm_bt<<<dim3(32, 32), 256, 0, stream>>>(hidden, qkv_w, qkv, 4096, 4096, 2048);
  norm_rope<<<dim3(4096, 24), 128, 0, stream>>>(qkv, qnw, knw, pos, qn, kn);
  transpose_v<<<dim3(64, 8), 256, 0, stream>>>(qkv, vt);
  attn<<<dim3(64, 8), 256, 0, stream>>>(qn, kn, vt, ao);
  gemm_bt<<<dim3(16, 32), 256, 0, stream>>>(ao, o_w, out, 4096, 2048, 2048);
}

// Round 4
// 825.610 us; speedup vs baseline: 1.2359x; 1.0521x over previous
//
#include <hip/hip_runtime.h>
#include <hip/hip_bf16.h>
#include <math.h>

// ---------------------------------------------------------------------------
// Qwen3 attention block: T=4096, HIDDEN=2048, 16 Q heads, 8 KV heads,
// HEAD_DIM=128, rope theta 1e6, rms eps 1e-6, causal.
// fp32 in/out; bf16 internally for MFMA with fp32 accumulation.
//
// ws layout (84 MB, regions reused across phases):
//   qkv  bf16 [4096][4096]  @ 0
//   qn   bf16 [4096][2048]  @ 16777216   (also wo after attn)
//   kn   bf16 [4096][1024]  @ 25165824   (kn+vt region doubles as wq pre-gemm1)
//   vt   bf16 [1024][4096]  @ 29360128
//   ao   bf16 [4096][2048]  @ 33554432   (doubles as hb pre-attn)
// ---------------------------------------------------------------------------

typedef __bf16 bf16;
typedef __bf16 bf16x4 __attribute__((ext_vector_type(4)));
typedef __bf16 bf16x8 __attribute__((ext_vector_type(8)));
typedef float  f32x4  __attribute__((ext_vector_type(4)));

__device__ __forceinline__ f32x4 mfma16(bf16x8 a, bf16x8 b, f32x4 c) {
  return __builtin_amdgcn_mfma_f32_16x16x32_bf16(a, b, c, 0, 0, 0);
}

__device__ __forceinline__ void load8_to_lds(const float* src, bf16* dst) {
  float4 a = *reinterpret_cast<const float4*>(src);
  float4 b = *reinterpret_cast<const float4*>(src + 4);
  bf16x8 v = {(bf16)a.x, (bf16)a.y, (bf16)a.z, (bf16)a.w,
              (bf16)b.x, (bf16)b.y, (bf16)b.z, (bf16)b.w};
  *reinterpret_cast<bf16x8*>(dst) = v;
}
__device__ __forceinline__ void load8_to_lds(const bf16* src, bf16* dst) {
  *reinterpret_cast<uint4*>(dst) = *reinterpret_cast<const uint4*>(src);
}
__device__ __forceinline__ void store_c(float* p, float v) { *p = v; }
__device__ __forceinline__ void store_c(bf16* p, float v) { *p = (bf16)v; }

// ---------------------------------------------------------------------------
// fp32 -> bf16 cast, 8 elems/thread
// ---------------------------------------------------------------------------
__global__ __launch_bounds__(256) void cast_bf16(const float* __restrict__ s,
                                                 bf16* __restrict__ d) {
  int i = blockIdx.x * 256 + threadIdx.x;
  float4 a = reinterpret_cast<const float4*>(s)[i * 2];
  float4 b = reinterpret_cast<const float4*>(s)[i * 2 + 1];
  bf16x8 v = {(bf16)a.x, (bf16)a.y, (bf16)a.z, (bf16)a.w,
              (bf16)b.x, (bf16)b.y, (bf16)b.z, (bf16)b.w};
  reinterpret_cast<bf16x8*>(d)[i] = v;
}

// ---------------------------------------------------------------------------
// C[M][N] = A[M][K] @ B[N][K]^T   (fp32 accumulate) — unchanged structure
// ---------------------------------------------------------------------------
template <typename TA, typename TB, typename TC>
__global__ __launch_bounds__(256) void gemm_bt(const TA* __restrict__ A,
                                               const TB* __restrict__ B,
                                               TC* __restrict__ C,
                                               int M, int N, int K) {
  __shared__ __align__(16) bf16 As[128 * 40];
  __shared__ __align__(16) bf16 Bs[128 * 40];

  const int tid  = threadIdx.x;
  const int wave = tid >> 6, lane = tid & 63;
  const int quad = lane >> 4, l16 = lane & 15;
  const int wm = (wave >> 1) * 64, wn = (wave & 1) * 64;
  const int n0 = blockIdx.x * 128, m0 = blockIdx.y * 128;

  const f32x4 zero = {0.f, 0.f, 0.f, 0.f};
  f32x4 acc[4][4];
#pragma unroll
  for (int i = 0; i < 4; ++i)
#pragma unroll
    for (int j = 0; j < 4; ++j) acc[i][j] = zero;

  for (int k0 = 0; k0 < K; k0 += 32) {
#pragma unroll
    for (int it = 0; it < 2; ++it) {
      int linear = it * 2048 + tid * 8;
      int r = linear >> 5, c = linear & 31;
      load8_to_lds(&A[(size_t)(m0 + r) * K + k0 + c], &As[r * 40 + c]);
      load8_to_lds(&B[(size_t)(n0 + r) * K + k0 + c], &Bs[r * 40 + c]);
    }
    __syncthreads();

    bf16x8 af[4], bfr[4];
#pragma unroll
    for (int i = 0; i < 4; ++i)
      af[i] = *reinterpret_cast<const bf16x8*>(&As[(wm + i * 16 + l16) * 40 + quad * 8]);
#pragma unroll
    for (int j = 0; j < 4; ++j)
      bfr[j] = *reinterpret_cast<const bf16x8*>(&Bs[(wn + j * 16 + l16) * 40 + quad * 8]);
#pragma unroll
    for (int i = 0; i < 4; ++i)
#pragma unroll
      for (int j = 0; j < 4; ++j)
        acc[i][j] = mfma16(af[i], bfr[j], acc[i][j]);
    __syncthreads();
  }

#pragma unroll
  for (int i = 0; i < 4; ++i)
#pragma unroll
    for (int j = 0; j < 4; ++j)
#pragma unroll
      for (int r = 0; r < 4; ++r) {
        int row = m0 + wm + i * 16 + quad * 4 + r;
        int col = n0 + wn + j * 16 + l16;
        store_c(&C[(size_t)row * N + col], acc[i][j][r]);
      }
}

// ---------------------------------------------------------------------------
// Per-(token, head) RMS norm + rope — unchanged
// ---------------------------------------------------------------------------
__global__ __launch_bounds__(128) void norm_rope(const bf16* __restrict__ qkv,
                                                 const float* __restrict__ qw,
                                                 const float* __restrict__ kw,
                                                 const int* __restrict__ pos,
                                                 bf16* __restrict__ qn,
                                                 bf16* __restrict__ kn) {
  const int t   = blockIdx.x;
  const int hr  = blockIdx.y;
  const int tid = threadIdx.x;
  const bool isq = hr < 16;
  const int col  = isq ? hr * 128 : 2048 + (hr - 16) * 128;

  float x = (float)qkv[(size_t)t * 4096 + col + tid];
  float ss = x * x;
#pragma unroll
  for (int o = 32; o >= 1; o >>= 1) ss += __shfl_xor(ss, o);
  __shared__ float part[2];
  __shared__ float sh[128];
  if ((tid & 63) == 0) part[tid >> 6] = ss;
  __syncthreads();
  float total = part[0] + part[1];
  float rms = rsqrtf(total * (1.0f / 128.0f) + 1e-6f);
  const float* w = isq ? qw : kw;
  float xn = x * rms * w[tid];
  sh[tid] = xn;
  __syncthreads();

  int d = tid & 63;
  float inv = exp2f((float)d * (-19.93156856932417f / 64.0f));
  float fr = (float)pos[t] * inv;
  float sn, cs;
  sincosf(fr, &sn, &cs);
  float out = (tid < 64) ? (sh[tid] * cs - sh[tid + 64] * sn)
                         : (sh[tid] * cs + sh[tid - 64] * sn);
  if (isq) qn[(size_t)t * 2048 + hr * 128 + tid] = (bf16)out;
  else     kn[(size_t)t * 1024 + (hr - 16) * 128 + tid] = (bf16)out;
}

// ---------------------------------------------------------------------------
// One-time V transpose — unchanged
// ---------------------------------------------------------------------------
__global__ __launch_bounds__(256) void transpose_v(const bf16* __restrict__ qkv,
                                                   bf16* __restrict__ vt) {
  __shared__ __align__(16) bf16 tile[128 * 72];
  const int t0 = blockIdx.x * 64, kvh = blockIdx.y;
  const int tid = threadIdx.x;
#pragma unroll
  for (int it = 0; it < 2; ++it) {
    int linear = it * 4096 + tid * 16;
    int r = linear >> 7, c = linear & 127;
    union { uint4 v; bf16 e[8]; } u0, u1;
    u0.v = *reinterpret_cast<const uint4*>(
        &qkv[(size_t)(t0 + r) * 4096 + 3072 + kvh * 128 + c]);
    u1.v = *reinterpret_cast<const uint4*>(
        &qkv[(size_t)(t0 + r) * 4096 + 3072 + kvh * 128 + c + 8]);
#pragma unroll
    for (int j = 0; j < 8; ++j) tile[(c + j) * 72 + r] = u0.e[j];
#pragma unroll
    for (int j = 0; j < 8; ++j) tile[(c + 8 + j) * 72 + r] = u1.e[j];
  }
  __syncthreads();
#pragma unroll
  for (int it = 0; it < 4; ++it) {
    int linear = it * 2048 + tid * 8;
    int d = linear >> 6, c = linear & 63;
    uint4 v = *reinterpret_cast<const uint4*>(&tile[d * 72 + c]);
    *reinterpret_cast<uint4*>(&vt[(size_t)(kvh * 128 + d) * 4096 + t0 + c]) = v;
  }
}

// ---------------------------------------------------------------------------
// Flash attention v3 (S^T formulation). grid (64 q-tiles, 8 kvh), block 256.
// waves 0-1 -> head 2*kvh, waves 2-3 -> head 2*kvh+1; wave&1 = 32-row q half.
// S^T = K.Q^T (C rows = kv t, cols = q) -> softmax over rows = in-lane regs +
// 2 cross-quad shuffles; P pack = 8x ds_write_b64; O^T = V^T.P.
// Register-prefetch of next K/V tile hides global latency.
// ---------------------------------------------------------------------------
__global__ __launch_bounds__(256) void attn(const bf16* __restrict__ q,
                                            const bf16* __restrict__ k,
                                            const bf16* __restrict__ vt,
                                            bf16* __restrict__ out) {
  __shared__ __align__(16) bf16 Ks[64 * 136];    // [kv row][dim]
  __shared__ __align__(16) bf16 Vs[128 * 72];    // [dim][kv row]
  __shared__ __align__(16) bf16 Ps[4][32 * 72];  // per wave [q col][kv t]

  const int kvh = blockIdx.y;
  const int bx  = blockIdx.x;
  // long/short balance that survives round-robin XCD dispatch (stride 8):
  // pair p gets {long 63-p, short p}; which bx of the pair is long flips with
  // (p>>2)&1 so each bx%8 class alternates long/short.
  const int p  = bx >> 1;
  const int qt = (((bx & 1) ^ ((p >> 2) & 1)) == 0) ? (63 - p) : p;
  const int q0 = qt * 64;
  const int kend = q0 + 64;

  const int tid = threadIdx.x;
  const int wave = tid >> 6, lane = tid & 63;
  const int quad = lane >> 4, l16 = lane & 15;
  const int head = 2 * kvh + (wave >> 1);
  const int mbase = q0 + (wave & 1) * 32;
  const float cExp = 0.08838834764831845f * 1.4426950408889634f; // scale*log2e

  // Q fragments (B-operand layout == A layout): B[n=l16][k=ks*32+quad*8+j]
  bf16x8 qf[2][4];
#pragma unroll
  for (int mi = 0; mi < 2; ++mi)
#pragma unroll
    for (int s = 0; s < 4; ++s)
      qf[mi][s] = *reinterpret_cast<const bf16x8*>(
          &q[(size_t)(mbase + mi * 16 + l16) * 2048 + head * 128 + s * 32 + quad * 8]);

  const f32x4 zero = {0.f, 0.f, 0.f, 0.f};
  f32x4 o_acc[8][2];  // O^T [d-tile][q-half]; elem: d=dt*16+quad*4+r, q=mi*16+l16
#pragma unroll
  for (int dt = 0; dt < 8; ++dt)
#pragma unroll
    for (int mi = 0; mi < 2; ++mi) o_acc[dt][mi] = zero;
  float m_i[2] = {-3.0e38f, -3.0e38f};
  float l_i[2] = {0.f, 0.f};

  // ---- prefetch tile 0 into registers ----
  uint4 pk[4], pv[4];
#pragma unroll
  for (int it = 0; it < 4; ++it) {
    int linear = it * 2048 + tid * 8;
    int r = linear >> 7, c = linear & 127;
    pk[it] = *reinterpret_cast<const uint4*>(&k[(size_t)r * 1024 + kvh * 128 + c]);
    int d = linear >> 6, c2 = linear & 63;
    pv[it] = *reinterpret_cast<const uint4*>(&vt[(size_t)(kvh * 128 + d) * 4096 + c2]);
  }

  for (int k0 = 0; k0 < kend; k0 += 64) {
    // ---- publish prefetched tile to LDS ----
#pragma unroll
    for (int it = 0; it < 4; ++it) {
      int linear = it * 2048 + tid * 8;
      int r = linear >> 7, c = linear & 127;
      *reinterpret_cast<uint4*>(&Ks[r * 136 + c]) = pk[it];
      int d = linear >> 6, c2 = linear & 63;
      *reinterpret_cast<uint4*>(&Vs[d * 72 + c2]) = pv[it];
    }
    __syncthreads();

    // ---- prefetch next tile (overlaps with compute below) ----
    if (k0 + 64 < kend) {
      int kn0 = k0 + 64;
#pragma unroll
      for (int it = 0; it < 4; ++it) {
        int linear = it * 2048 + tid * 8;
        int r = linear >> 7, c = linear & 127;
        pk[it] = *reinterpret_cast<const uint4*>(
            &k[(size_t)(kn0 + r) * 1024 + kvh * 128 + c]);
        int d = linear >> 6, c2 = linear & 63;
        pv[it] = *reinterpret_cast<const uint4*>(
            &vt[(size_t)(kvh * 128 + d) * 4096 + kn0 + c2]);
      }
    }

    // ---- S^T = K Q^T : rows t (4 tiles), cols q (2 tiles) ----
    f32x4 s_acc[4][2];
#pragma unroll
    for (int mt = 0; mt < 4; ++mt) {
      bf16x8 kf[4];
#pragma unroll
      for (int ks = 0; ks < 4; ++ks)
        kf[ks] = *reinterpret_cast<const bf16x8*>(
            &Ks[(mt * 16 + l16) * 136 + ks * 32 + quad * 8]);
#pragma unroll
      for (int mi = 0; mi < 2; ++mi) {
        f32x4 sa = zero;
#pragma unroll
        for (int ks = 0; ks < 4; ++ks) sa = mfma16(kf[ks], qf[mi][ks], sa);
        s_acc[mt][mi] = sa;
      }
    }

    // ---- causal mask (diagonal tile only): t > q  ->  -inf ----
    if (k0 == q0) {
#pragma unroll
      for (int mt = 0; mt < 4; ++mt)
#pragma unroll
        for (int mi = 0; mi < 2; ++mi) {
          int tq = (wave & 1) * 32 + mi * 16 + l16;
#pragma unroll
          for (int r = 0; r < 4; ++r) {
            int tk = mt * 16 + quad * 4 + r;
            if (tk > tq) s_acc[mt][mi][r] = -3.0e38f;
          }
        }
    }

    // ---- online softmax: per q (lane-fixed), reduce over in-lane regs + quads
#pragma unroll
    for (int mi = 0; mi < 2; ++mi) {
      float mx = -3.0e38f;
#pragma unroll
      for (int mt = 0; mt < 4; ++mt)
#pragma unroll
        for (int r = 0; r < 4; ++r) mx = fmaxf(mx, s_acc[mt][mi][r]);
      mx = fmaxf(mx, __shfl_xor(mx, 16));
      mx = fmaxf(mx, __shfl_xor(mx, 32));
      float mn = fmaxf(m_i[mi], mx);
      float al = exp2f((m_i[mi] - mn) * cExp);
      m_i[mi] = mn;
      float nmc = -mn * cExp;
      float rs = 0.f;
#pragma unroll
      for (int mt = 0; mt < 4; ++mt)
#pragma unroll
        for (int r = 0; r < 4; ++r) {
          float pe = exp2f(fmaf(s_acc[mt][mi][r], cExp, nmc));
          s_acc[mt][mi][r] = pe;
          rs += pe;
        }
      rs += __shfl_xor(rs, 16);
      rs += __shfl_xor(rs, 32);
      l_i[mi] = l_i[mi] * al + rs;
      if (__any(al < 1.0f)) {
#pragma unroll
        for (int dt = 0; dt < 8; ++dt)
#pragma unroll
          for (int r = 0; r < 4; ++r) o_acc[dt][mi][r] *= al;
      }
    }

    // ---- P -> LDS [q][t]: 4 contiguous t per reg-quad -> ds_write_b64 ----
#pragma unroll
    for (int mt = 0; mt < 4; ++mt)
#pragma unroll
      for (int mi = 0; mi < 2; ++mi) {
        bf16x4 pkv;
#pragma unroll
        for (int r = 0; r < 4; ++r) pkv[r] = (bf16)s_acc[mt][mi][r];
        *reinterpret_cast<bf16x4*>(
            &Ps[wave][(mi * 16 + l16) * 72 + mt * 16 + quad * 4]) = pkv;
      }
    // wave-private: compiler's lgkmcnt ordering suffices, no barrier

    // ---- O^T += V^T P : A = V^T (m=d), B = P (n=q) ----
#pragma unroll
    for (int ks = 0; ks < 2; ++ks) {
      bf16x8 pb[2];
#pragma unroll
      for (int mi = 0; mi < 2; ++mi)
        pb[mi] = *reinterpret_cast<const bf16x8*>(
            &Ps[wave][(mi * 16 + l16) * 72 + ks * 32 + quad * 8]);
#pragma unroll
      for (int dt = 0; dt < 8; ++dt) {
        bf16x8 va = *reinterpret_cast<const bf16x8*>(
            &Vs[(dt * 16 + l16) * 72 + ks * 32 + quad * 8]);
#pragma unroll
        for (int mi = 0; mi < 2; ++mi)
          o_acc[dt][mi] = mfma16(va, pb[mi], o_acc[dt][mi]);
      }
    }
    __syncthreads();  // all waves done with Ks/Vs before next publish
  }

  // ---- epilogue: O = O^T/l, rows q, 4 contiguous d per reg-quad ----
#pragma unroll
  for (int mi = 0; mi < 2; ++mi) {
    float rl = __builtin_amdgcn_rcpf(l_i[mi]);
    int trow = mbase + mi * 16 + l16;
#pragma unroll
    for (int dt = 0; dt < 8; ++dt) {
      bf16x4 ov;
#pragma unroll
      for (int r = 0; r < 4; ++r) ov[r] = (bf16)(o_acc[dt][mi][r] * rl);
      *reinterpret_cast<bf16x4*>(
          &out[(size_t)trow * 2048 + head * 128 + dt * 16 + quad * 4]) = ov;
    }
  }
}

// ---------------------------------------------------------------------------
extern "C" void kernel_launch(void* const* d_in, const int* in_sizes, int n_in,
                              void* d_out, int out_size, void* d_ws, size_t ws_size,
                              hipStream_t stream) {
  const float* hidden = (const float*)d_in[0];
  const float* qkv_w  = (const float*)d_in[1];
  const float* qnw    = (const float*)d_in[2];
  const float* knw    = (const float*)d_in[3];
  const float* o_w    = (const float*)d_in[4];
  const int*   pos    = (const int*)d_in[5];

  bf16* qkv = (bf16*)d_ws;                       // 4096*4096
  bf16* qn  = qkv + (size_t)4096 * 4096;         // 4096*2048
  bf16* kn  = qn  + (size_t)4096 * 2048;         // 4096*1024
  bf16* vt  = kn  + (size_t)4096 * 1024;         // 1024*4096
  bf16* ao  = vt  + (size_t)1024 * 4096;         // 4096*2048
  // region reuse (all disjoint in time):
  bf16* hb  = ao;   // bf16 hidden, dead before attn writes ao
  bf16* wq  = kn;   // bf16 qkv_w, dead before norm_rope/transpose write kn/vt
  bf16* wo  = qn;   // bf16 o_w, cast after attn (qn dead)
  float* out = (float*)d_out;

  cast_bf16<<<4096, 256, 0, stream>>>(hidden, hb);
  cast_bf16<<<4096, 256, 0, stream>>>(qkv_w, wq);
  gemm_bt<<<dim3(32, 32), 256, 0, stream>>>(hb, wq, qkv, 4096, 4096, 2048);
  norm_rope<<<dim3(4096, 24), 128, 0, stream>>>(qkv, qnw, knw, pos, qn, kn);
  transpose_v<<<dim3(64, 8), 256, 0, stream>>>(qkv, vt);
  attn<<<dim3(64, 8), 256, 0, stream>>>(qn, kn, vt, ao);
  cast_bf16<<<2048, 256, 0, stream>>>(o_w, wo);
  gemm_bt<<<dim3(16, 32), 256, 0, stream>>>(ao, wo, out, 4096, 2048, 2048);
}